// Round 3
// baseline (5446.039 us; speedup 1.0000x reference)
//
#include <hip/hip_runtime.h>
#include <stdint.h>

typedef __bf16  bf16x8 __attribute__((ext_vector_type(8)));
typedef float   f32x4  __attribute__((ext_vector_type(4)));
typedef unsigned short u16;

#define TEMP 5.0f

// ---------- helpers ----------
__device__ inline float wsum(float v){
  #pragma unroll
  for (int off=32; off; off>>=1) v += __shfl_xor(v, off, 64);
  return v;
}
__device__ inline float wmax(float v){
  #pragma unroll
  for (int off=32; off; off>>=1) v = fmaxf(v, __shfl_xor(v, off, 64));
  return v;
}
__device__ inline float wmin(float v){
  #pragma unroll
  for (int off=32; off; off>>=1) v = fminf(v, __shfl_xor(v, off, 64));
  return v;
}
__device__ inline u16 f2bf(float f){               // RNE float->bf16
  unsigned u = __float_as_uint(f);
  u = u + 0x7fffu + ((u>>16)&1u);
  return (u16)(u>>16);
}
__device__ inline float bfl(unsigned u){ return __uint_as_float(u<<16); }
__device__ inline float bfh(unsigned u){ return __uint_as_float(u & 0xffff0000u); }

// ---------- K0: normalize image features (32x512) ----------
__global__ void k_img(const float* __restrict__ X, float* __restrict__ imgn){
  int b = blockIdx.x, lane = threadIdx.x;
  const float* src = X + (size_t)b*512 + lane*8;
  float4 a = *(const float4*)src;
  float4 c = *(const float4*)(src+4);
  float ss = a.x*a.x+a.y*a.y+a.z*a.z+a.w*a.w + c.x*c.x+c.y*c.y+c.z*c.z+c.w*c.w;
  ss = wsum(ss);
  float inv = 1.0f/sqrtf(ss);
  float* dst = imgn + (size_t)b*512 + lane*8;
  float4 o0 = {a.x*inv,a.y*inv,a.z*inv,a.w*inv};
  float4 o1 = {c.x*inv,c.y*inv,c.z*inv,c.w*inv};
  *(float4*)dst = o0; *(float4*)(dst+4) = o1;
}

// ---------- K1: normalize txt; write bf16 K-chunked layout TXT[kc][cn][32]; invn[n*1000+c] ----------
// cn = c*51+n, padded to 51008 rows (pad rows zero)
__global__ void k_txt(const float* __restrict__ X, u16* __restrict__ TXT, float* __restrict__ invn){
  int cn = blockIdx.x, lane = threadIdx.x;
  int kc = lane>>2, kk8 = (lane&3)*8;
  size_t dstE = ((size_t)kc*51008 + cn)*32 + kk8;
  if (cn >= 51000){
    uint4 z = {0,0,0,0};
    *(uint4*)(TXT + dstE) = z;
    return;
  }
  int c = cn/51, n = cn - c*51;
  const float* src = X + ((size_t)n*1000 + c)*512 + lane*8;
  float4 a = *(const float4*)src;
  float4 d = *(const float4*)(src+4);
  float ss = a.x*a.x+a.y*a.y+a.z*a.z+a.w*a.w + d.x*d.x+d.y*d.y+d.z*d.z+d.w*d.w;
  ss = wsum(ss);
  float inv = 1.0f/sqrtf(ss);
  u16 h0=f2bf(a.x*inv),h1=f2bf(a.y*inv),h2=f2bf(a.z*inv),h3=f2bf(a.w*inv);
  u16 h4=f2bf(d.x*inv),h5=f2bf(d.y*inv),h6=f2bf(d.z*inv),h7=f2bf(d.w*inv);
  uint4 o;
  o.x = (unsigned)h0 | ((unsigned)h1<<16);
  o.y = (unsigned)h2 | ((unsigned)h3<<16);
  o.z = (unsigned)h4 | ((unsigned)h5<<16);
  o.w = (unsigned)h6 | ((unsigned)h7<<16);
  *(uint4*)(TXT + dstE) = o;
  if (lane==0) invn[(size_t)n*1000 + c] = inv;
}

// ---------- K2: mean_txt[c] = l2norm( sum_n txt_n[c] ) (fp32 precise) ----------
__global__ void k_mean(const float* __restrict__ X, const float* __restrict__ invn, float* __restrict__ MT){
  int c = blockIdx.x, tid = threadIdx.x, lane = tid&63, wv = tid>>6;
  __shared__ float sinv[51];
  __shared__ float red[4];
  if (tid < 51) sinv[tid] = invn[(size_t)tid*1000 + c];
  __syncthreads();
  int d0 = tid*2;
  float sx=0.f, sy=0.f;
  for (int n=0;n<51;++n){
    const float2 x = *(const float2*)(X + ((size_t)n*1000 + c)*512 + d0);
    float iv = sinv[n];
    sx += x.x*iv; sy += x.y*iv;
  }
  float ss = sx*sx + sy*sy;
  ss = wsum(ss);
  if (lane==0) red[wv] = ss;
  __syncthreads();
  float tot = red[0]+red[1]+red[2]+red[3];
  float inv = 1.0f/sqrtf(tot);
  float2 o = {sx*inv, sy*inv};
  *(float2*)(MT + (size_t)c*512 + d0) = o;
}

// ---------- K3: v[c,n] = softmax_n( TEMP * mean_txt[c].txt[n,c] ) ----------
__global__ void k_v(const u16* __restrict__ TXT, const float* __restrict__ MT, float* __restrict__ vbuf){
  int c = blockIdx.x, lane = threadIdx.x;
  __shared__ float lg[51];
  const float* mp = MT + (size_t)c*512 + lane*8;
  float4 m0 = *(const float4*)mp;
  float4 m1 = *(const float4*)(mp+4);
  int kc = lane>>2, kk8 = (lane&3)*8;
  for (int n=0;n<51;++n){
    size_t e = ((size_t)kc*51008 + (size_t)(c*51+n))*32 + kk8;
    uint4 q = *(const uint4*)(TXT + e);
    float d = bfl(q.x)*m0.x + bfh(q.x)*m0.y + bfl(q.y)*m0.z + bfh(q.y)*m0.w
            + bfl(q.z)*m1.x + bfh(q.z)*m1.y + bfl(q.w)*m1.z + bfh(q.w)*m1.w;
    d = wsum(d);
    if (lane==0) lg[n] = d;
  }
  __syncthreads();
  float val = (lane<51) ? lg[lane] : -1e30f;
  float mx = wmax(val);
  float e = (lane<51) ? expf(TEMP*(val-mx)) : 0.f;
  float s = wsum(e);
  if (lane<51) vbuf[(size_t)c*51 + lane] = e/s;
}

// ---------- K4: bias[b,c] = base_logits = img_n[b].mean_txt[c] ----------
__global__ void k_base(const float* __restrict__ imgn, const float* __restrict__ MT, float* __restrict__ bias){
  int c = blockIdx.x, lane = threadIdx.x;
  const float* mp = MT + (size_t)c*512 + lane*8;
  float4 m0 = *(const float4*)mp;
  float4 m1 = *(const float4*)(mp+4);
  for (int b=0;b<32;++b){
    const float* ip = imgn + (size_t)b*512 + lane*8;
    float4 i0 = *(const float4*)ip;
    float4 i1 = *(const float4*)(ip+4);
    float d = i0.x*m0.x+i0.y*m0.y+i0.z*m0.z+i0.w*m0.w
            + i1.x*m1.x+i1.y*m1.y+i1.z*m1.z+i1.w*m1.w;
    d = wsum(d);
    if (lane==0) bias[(size_t)b*1000 + c] = d;
  }
}

// ---------- K5: normalize loc; LOC[b][kc][m(224 pad)][32] bf16; ew[b,m]=exp(5*img.loc) ----------
__global__ void k_loc(const float* __restrict__ L, const float* __restrict__ imgn,
                      u16* __restrict__ LOC, float* __restrict__ ewg){
  int m = blockIdx.x, b = blockIdx.y, lane = threadIdx.x;
  size_t dstE = ((size_t)(b*16 + (lane>>2))*224 + m)*32 + (lane&3)*8;
  if (m >= 196){
    uint4 z = {0,0,0,0};
    *(uint4*)(LOC + dstE) = z;
    if (lane==0) ewg[(size_t)b*224 + m] = 0.f;
    return;
  }
  const float* src = L + ((size_t)b*196 + m)*512 + lane*8;
  float4 a = *(const float4*)src;
  float4 d = *(const float4*)(src+4);
  const float* ip = imgn + (size_t)b*512 + lane*8;
  float4 i0 = *(const float4*)ip;
  float4 i1 = *(const float4*)(ip+4);
  float ss = a.x*a.x+a.y*a.y+a.z*a.z+a.w*a.w + d.x*d.x+d.y*d.y+d.z*d.z+d.w*d.w;
  float ws = a.x*i0.x+a.y*i0.y+a.z*i0.z+a.w*i0.w + d.x*i1.x+d.y*i1.y+d.z*i1.z+d.w*i1.w;
  ss = wsum(ss); ws = wsum(ws);
  float inv = 1.0f/sqrtf(ss);
  u16 h0=f2bf(a.x*inv),h1=f2bf(a.y*inv),h2=f2bf(a.z*inv),h3=f2bf(a.w*inv);
  u16 h4=f2bf(d.x*inv),h5=f2bf(d.y*inv),h6=f2bf(d.z*inv),h7=f2bf(d.w*inv);
  uint4 o;
  o.x = (unsigned)h0 | ((unsigned)h1<<16);
  o.y = (unsigned)h2 | ((unsigned)h3<<16);
  o.z = (unsigned)h4 | ((unsigned)h5<<16);
  o.w = (unsigned)h6 | ((unsigned)h7<<16);
  *(uint4*)(LOC + dstE) = o;
  if (lane==0) ewg[(size_t)b*224 + m] = expf(TEMP * ws * inv);
}

// ---------- K6: fused GEMM (MFMA bf16) + top-50 + weighted sum -> atomicAdd bias ----------
// 1D grid 25504, b = idx&31 (fast: resident blocks share TXT tiles), cn-tile = idx>>5.
// 256 thr (4 waves). Tile M=224, N=64, K=512 in 16 kc-steps of 32.
// Distance-2 pipeline: iter kc computes LDS[kc&1]; stores regs holding tile kc+1
// (loaded at iter kc-1) into LDS[(kc+1)&1]; issues global load of tile kc+2.
// LDS 28 KB (A dbuf). Epilogue reuses it: 4 phases x 16 cols, S[16][228]+ew = 15.5 KB.
__global__ __launch_bounds__(256,3) void k_main(const u16* __restrict__ TXT, const u16* __restrict__ LOC,
                                                const float* __restrict__ ewg, const float* __restrict__ vbuf,
                                                float* __restrict__ bias){
  __shared__ __align__(16) char smem[28672];
  const int tid = threadIdx.x, lane = tid & 63, wv = tid >> 6;
  const int quad = lane >> 4, l16 = lane & 15;
  const int ms = wv >> 1, ns = wv & 1;
  const int idx = blockIdx.x;
  const int b   = idx & 31;
  const int cn0 = (idx >> 5) * 64;

  const f32x4 zero = {0.f,0.f,0.f,0.f};
  f32x4 acc[7][2];
  #pragma unroll
  for (int t=0;t<7;++t){ acc[t][0]=zero; acc[t][1]=zero; }

  const u16* Abase = LOC + (size_t)(b*16)*224*32;
  char* Albd0 = smem;
  char* Albd1 = smem + 14336;
  uint4 rA[4], rB[4];

  auto issueA = [&](int kc, uint4* r){
    const char* src = (const char*)(Abase + (size_t)kc*224*32);
    #pragma unroll
    for (int j=0;j<4;++j){ int ch = tid + j*256; if (ch < 896) r[j] = *(const uint4*)(src + ch*16); }
  };
  auto storeA = [&](uint4* r, char* dst){
    #pragma unroll
    for (int j=0;j<4;++j){ int ch = tid + j*256; if (ch < 896) *(uint4*)(dst + ch*16) = r[j]; }
  };
  auto loadB = [&](int kc, bf16x8* bf){
    #pragma unroll
    for (int j2=0;j2<2;++j2){
      size_t e = ((size_t)kc*51008 + (size_t)(cn0 + 32*ns + 16*j2 + l16))*32 + quad*8;
      bf[j2] = *(const bf16x8*)(TXT + e);
    }
  };
  auto domfma = [&](const char* Ab, bf16x8* bf){
    #pragma unroll
    for (int t=0;t<7;++t){
      bf16x8 af = *(const bf16x8*)(Ab + (size_t)((112*ms + 16*t + l16)*64 + quad*16));
      acc[t][0] = __builtin_amdgcn_mfma_f32_16x16x32_bf16(af, bf[0], acc[t][0], 0,0,0);
      acc[t][1] = __builtin_amdgcn_mfma_f32_16x16x32_bf16(af, bf[1], acc[t][1], 0,0,0);
    }
  };

  bf16x8 bcur[2], bnext[2];
  issueA(0, rA); loadB(0, bcur);
  storeA(rA, Albd0);            // waits the global load; one-time cost
  issueA(1, rB);
  __syncthreads();

  for (int kc = 0; kc < 16; kc += 2){
    // even step: compute tile kc from LDS0
    if (kc+1 < 16) loadB(kc+1, bnext);
    if (kc+2 < 16) issueA(kc+2, rA);
    domfma(Albd0, bcur);
    if (kc+1 < 16) storeA(rB, Albd1);   // tile kc+1, loaded one iter ago
    __syncthreads();
    if (kc+1 < 16){
      // odd step: compute tile kc+1 from LDS1
      if (kc+2 < 16) loadB(kc+2, bcur);
      if (kc+3 < 16) issueA(kc+3, rB);
      domfma(Albd1, bnext);
      if (kc+2 < 16) storeA(rA, Albd0); // tile kc+2
      __syncthreads();
    }
  }

  // ---- epilogue: 4 phases of 16 columns; S[16][228] f32 + ew[224] reuse staging LDS ----
  float* S   = (float*)smem;             // 16*228*4 = 14592 B
  float* ewl = (float*)(smem + 14592);   // 224*4 = 896 B  (total 15488 <= 28672)
  if (tid < 224) ewl[tid] = ewg[(size_t)b*224 + tid];
  __syncthreads();
  float e0=0.f,e1=0.f,e2=0.f,e3=0.f;
  if (lane < 49){ const float* p = ewl + 4*lane; e0=p[0]; e1=p[1]; e2=p[2]; e3=p[3]; }

  for (int ph=0; ph<4; ++ph){
    // writers: waves with ns == ph>>1 hold the acc for col group ph (j2 = ph&1)
    if (ns == (ph>>1)){
      int j2 = ph & 1;
      #pragma unroll
      for (int t=0;t<7;++t){
        int m0 = 112*ms + 16*t + quad*4;
        *(f32x4*)(S + (size_t)l16*228 + m0) = acc[t][j2];
      }
    }
    __syncthreads();

    // each wave processes 4 of the 16 columns
    #pragma unroll
    for (int i=0;i<4;++i){
      int nl = wv*4 + i;
      int cn = cn0 + ph*16 + nl;
      if (cn < 51000){
        float s0,s1,s2,s3;
        if (lane < 49){
          const float* p = S + (size_t)nl*228 + 4*lane;
          s0=p[0]; s1=p[1]; s2=p[2]; s3=p[3];
        } else { s0=s1=s2=s3=-1e30f; }

        // bracket from column min/max, then bisect for the top-50 threshold
        float vmax = wmax(fmaxf(fmaxf(s0,s1),fmaxf(s2,s3)));
        float fmn0 = (lane<49) ? fminf(fminf(s0,s1),fminf(s2,s3)) : 1e30f;
        float vmin = wmin(fmn0);
        float lo = vmin - 1e-6f, hi = vmax + 1e-6f, thr = lo;
        for (int it=0; it<30; ++it){
          float t = 0.5f*(lo+hi);
          unsigned long long b0=__ballot(s0>=t), b1=__ballot(s1>=t), b2=__ballot(s2>=t), b3=__ballot(s3>=t);
          int cnt = __popcll(b0)+__popcll(b1)+__popcll(b2)+__popcll(b3);
          if (cnt==50){ thr=t; break; }
          if (cnt>50) lo=t; else hi=t;
          thr = lo;
        }

        float num=0.f, den=0.f;
        if (s0>=thr){ num += s0*e0; den += e0; }
        if (s1>=thr){ num += s1*e1; den += e1; }
        if (s2>=thr){ num += s2*e2; den += e2; }
        if (s3>=thr){ num += s3*e3; den += e3; }
        num = wsum(num); den = wsum(den);
        if (lane==0){
          int c = cn/51;
          atomicAdd(bias + (size_t)b*1000 + c, vbuf[cn]*(num/den));
        }
      }
    }
    __syncthreads();   // S reads done before next phase overwrites
  }
}

// ---------- K7: out = fp32( exp(logit_scale) * bias ) ----------
__global__ void k_out(const float* __restrict__ bias, const float* __restrict__ ls, float* __restrict__ out){
  int i = blockIdx.x*256 + threadIdx.x;
  if (i < 32000){
    float sc = expf(ls[0]);
    out[i] = sc * bias[i];
  }
}

// ---------- launch ----------
extern "C" void kernel_launch(void* const* d_in, const int* in_sizes, int n_in,
                              void* d_out, int out_size, void* d_ws, size_t ws_size,
                              hipStream_t stream) {
  const float* img = (const float*)d_in[0];
  const float* loc = (const float*)d_in[1];
  const float* txt = (const float*)d_in[2];
  const float* ls  = (const float*)d_in[3];
  char* ws = (char*)d_ws;
  float* imgn = (float*)(ws + 0);            //  65536
  float* MT   = (float*)(ws + 65536);        //  2048000
  float* invn = (float*)(ws + 2113536);      //  204032
  float* vbuf = (float*)(ws + 2317568);      //  204032
  float* ewg  = (float*)(ws + 2521600);      //  28672
  float* bias = (float*)(ws + 2550272);      //  128000
  u16*   TXT  = (u16*)  (ws + 2678272);      //  52232192
  u16*   LOC  = (u16*)  (ws + 54910464);     //  7340032

  k_img <<<dim3(32),      dim3(64),  0, stream>>>(img, imgn);
  k_txt <<<dim3(51008),   dim3(64),  0, stream>>>(txt, TXT, invn);
  k_mean<<<dim3(1000),    dim3(256), 0, stream>>>(txt, invn, MT);
  k_v   <<<dim3(1000),    dim3(64),  0, stream>>>(TXT, MT, vbuf);
  k_base<<<dim3(1000),    dim3(64),  0, stream>>>(imgn, MT, bias);
  k_loc <<<dim3(224,32),  dim3(64),  0, stream>>>(loc, imgn, LOC, ewg);
  k_main<<<dim3(25504),   dim3(256), 0, stream>>>(TXT, LOC, ewg, vbuf, bias);
  k_out <<<dim3(125),     dim3(256), 0, stream>>>(bias, ls, (float*)d_out);
}

// Round 4
// 3498.414 us; speedup vs baseline: 1.5567x; 1.5567x over previous
//
#include <hip/hip_runtime.h>
#include <stdint.h>

typedef __bf16  bf16x8 __attribute__((ext_vector_type(8)));
typedef float   f32x4  __attribute__((ext_vector_type(4)));
typedef unsigned short u16;

#define TEMP 5.0f

// ---------- helpers ----------
__device__ inline float wsum(float v){
  #pragma unroll
  for (int off=32; off; off>>=1) v += __shfl_xor(v, off, 64);
  return v;
}
__device__ inline float wmax(float v){
  #pragma unroll
  for (int off=32; off; off>>=1) v = fmaxf(v, __shfl_xor(v, off, 64));
  return v;
}
__device__ inline float wmin(float v){
  #pragma unroll
  for (int off=32; off; off>>=1) v = fminf(v, __shfl_xor(v, off, 64));
  return v;
}
__device__ inline u16 f2bf(float f){               // RNE float->bf16
  unsigned u = __float_as_uint(f);
  u = u + 0x7fffu + ((u>>16)&1u);
  return (u16)(u>>16);
}
__device__ inline float bfl(unsigned u){ return __uint_as_float(u<<16); }
__device__ inline float bfh(unsigned u){ return __uint_as_float(u & 0xffff0000u); }

// async 16B global->LDS: lds dst is WAVE-UNIFORM base, HW adds lane*16
__device__ inline void cp16(void* lds_uniform, const void* g){
  __builtin_amdgcn_global_load_lds(
    (const __attribute__((address_space(1))) unsigned int*)g,
    (__attribute__((address_space(3))) unsigned int*)lds_uniform, 16, 0, 0);
}

// ---------- K0: normalize image features (32x512) ----------
__global__ void k_img(const float* __restrict__ X, float* __restrict__ imgn){
  int b = blockIdx.x, lane = threadIdx.x;
  const float* src = X + (size_t)b*512 + lane*8;
  float4 a = *(const float4*)src;
  float4 c = *(const float4*)(src+4);
  float ss = a.x*a.x+a.y*a.y+a.z*a.z+a.w*a.w + c.x*c.x+c.y*c.y+c.z*c.z+c.w*c.w;
  ss = wsum(ss);
  float inv = 1.0f/sqrtf(ss);
  float* dst = imgn + (size_t)b*512 + lane*8;
  float4 o0 = {a.x*inv,a.y*inv,a.z*inv,a.w*inv};
  float4 o1 = {c.x*inv,c.y*inv,c.z*inv,c.w*inv};
  *(float4*)dst = o0; *(float4*)(dst+4) = o1;
}

// ---------- K1: normalize txt; bf16 K-chunked TXT[kc][cn][32]; invn[n*1000+c] ----------
__global__ void k_txt(const float* __restrict__ X, u16* __restrict__ TXT, float* __restrict__ invn){
  int cn = blockIdx.x, lane = threadIdx.x;
  int kc = lane>>2, kk8 = (lane&3)*8;
  size_t dstE = ((size_t)kc*51008 + cn)*32 + kk8;
  if (cn >= 51000){
    uint4 z = {0,0,0,0};
    *(uint4*)(TXT + dstE) = z;
    return;
  }
  int c = cn/51, n = cn - c*51;
  const float* src = X + ((size_t)n*1000 + c)*512 + lane*8;
  float4 a = *(const float4*)src;
  float4 d = *(const float4*)(src+4);
  float ss = a.x*a.x+a.y*a.y+a.z*a.z+a.w*a.w + d.x*d.x+d.y*d.y+d.z*d.z+d.w*d.w;
  ss = wsum(ss);
  float inv = 1.0f/sqrtf(ss);
  u16 h0=f2bf(a.x*inv),h1=f2bf(a.y*inv),h2=f2bf(a.z*inv),h3=f2bf(a.w*inv);
  u16 h4=f2bf(d.x*inv),h5=f2bf(d.y*inv),h6=f2bf(d.z*inv),h7=f2bf(d.w*inv);
  uint4 o;
  o.x = (unsigned)h0 | ((unsigned)h1<<16);
  o.y = (unsigned)h2 | ((unsigned)h3<<16);
  o.z = (unsigned)h4 | ((unsigned)h5<<16);
  o.w = (unsigned)h6 | ((unsigned)h7<<16);
  *(uint4*)(TXT + dstE) = o;
  if (lane==0) invn[(size_t)n*1000 + c] = inv;
}

// ---------- K2: mean_txt[c] = l2norm( sum_n txt_n[c] ) ----------
__global__ void k_mean(const float* __restrict__ X, const float* __restrict__ invn, float* __restrict__ MT){
  int c = blockIdx.x, tid = threadIdx.x, lane = tid&63, wv = tid>>6;
  __shared__ float sinv[51];
  __shared__ float red[4];
  if (tid < 51) sinv[tid] = invn[(size_t)tid*1000 + c];
  __syncthreads();
  int d0 = tid*2;
  float sx=0.f, sy=0.f;
  for (int n=0;n<51;++n){
    const float2 x = *(const float2*)(X + ((size_t)n*1000 + c)*512 + d0);
    float iv = sinv[n];
    sx += x.x*iv; sy += x.y*iv;
  }
  float ss = sx*sx + sy*sy;
  ss = wsum(ss);
  if (lane==0) red[wv] = ss;
  __syncthreads();
  float tot = red[0]+red[1]+red[2]+red[3];
  float inv = 1.0f/sqrtf(tot);
  float2 o = {sx*inv, sy*inv};
  *(float2*)(MT + (size_t)c*512 + d0) = o;
}

// ---------- K3: v[c,n] = softmax_n( TEMP * mean_txt[c].txt[n,c] ) ----------
__global__ void k_v(const u16* __restrict__ TXT, const float* __restrict__ MT, float* __restrict__ vbuf){
  int c = blockIdx.x, lane = threadIdx.x;
  __shared__ float lg[51];
  const float* mp = MT + (size_t)c*512 + lane*8;
  float4 m0 = *(const float4*)mp;
  float4 m1 = *(const float4*)(mp+4);
  int kc = lane>>2, kk8 = (lane&3)*8;
  for (int n=0;n<51;++n){
    size_t e = ((size_t)kc*51008 + (size_t)(c*51+n))*32 + kk8;
    uint4 q = *(const uint4*)(TXT + e);
    float d = bfl(q.x)*m0.x + bfh(q.x)*m0.y + bfl(q.y)*m0.z + bfh(q.y)*m0.w
            + bfl(q.z)*m1.x + bfh(q.z)*m1.y + bfl(q.w)*m1.z + bfh(q.w)*m1.w;
    d = wsum(d);
    if (lane==0) lg[n] = d;
  }
  __syncthreads();
  float val = (lane<51) ? lg[lane] : -1e30f;
  float mx = wmax(val);
  float e = (lane<51) ? expf(TEMP*(val-mx)) : 0.f;
  float s = wsum(e);
  if (lane<51) vbuf[(size_t)c*51 + lane] = e/s;
}

// ---------- K4: bias[b,c] = base_logits ----------
__global__ void k_base(const float* __restrict__ imgn, const float* __restrict__ MT, float* __restrict__ bias){
  int c = blockIdx.x, lane = threadIdx.x;
  const float* mp = MT + (size_t)c*512 + lane*8;
  float4 m0 = *(const float4*)mp;
  float4 m1 = *(const float4*)(mp+4);
  for (int b=0;b<32;++b){
    const float* ip = imgn + (size_t)b*512 + lane*8;
    float4 i0 = *(const float4*)ip;
    float4 i1 = *(const float4*)(ip+4);
    float d = i0.x*m0.x+i0.y*m0.y+i0.z*m0.z+i0.w*m0.w
            + i1.x*m1.x+i1.y*m1.y+i1.z*m1.z+i1.w*m1.w;
    d = wsum(d);
    if (lane==0) bias[(size_t)b*1000 + c] = d;
  }
}

// ---------- K5: normalize loc; LOC[b][kc][m(224)][32] bf16; ew[b,m] ----------
__global__ void k_loc(const float* __restrict__ L, const float* __restrict__ imgn,
                      u16* __restrict__ LOC, float* __restrict__ ewg){
  int m = blockIdx.x, b = blockIdx.y, lane = threadIdx.x;
  size_t dstE = ((size_t)(b*16 + (lane>>2))*224 + m)*32 + (lane&3)*8;
  if (m >= 196){
    uint4 z = {0,0,0,0};
    *(uint4*)(LOC + dstE) = z;
    if (lane==0) ewg[(size_t)b*224 + m] = 0.f;
    return;
  }
  const float* src = L + ((size_t)b*196 + m)*512 + lane*8;
  float4 a = *(const float4*)src;
  float4 d = *(const float4*)(src+4);
  const float* ip = imgn + (size_t)b*512 + lane*8;
  float4 i0 = *(const float4*)ip;
  float4 i1 = *(const float4*)(ip+4);
  float ss = a.x*a.x+a.y*a.y+a.z*a.z+a.w*a.w + d.x*d.x+d.y*d.y+d.z*d.z+d.w*d.w;
  float ws = a.x*i0.x+a.y*i0.y+a.z*i0.z+a.w*i0.w + d.x*i1.x+d.y*i1.y+d.z*i1.z+d.w*i1.w;
  ss = wsum(ss); ws = wsum(ws);
  float inv = 1.0f/sqrtf(ss);
  u16 h0=f2bf(a.x*inv),h1=f2bf(a.y*inv),h2=f2bf(a.z*inv),h3=f2bf(a.w*inv);
  u16 h4=f2bf(d.x*inv),h5=f2bf(d.y*inv),h6=f2bf(d.z*inv),h7=f2bf(d.w*inv);
  uint4 o;
  o.x = (unsigned)h0 | ((unsigned)h1<<16);
  o.y = (unsigned)h2 | ((unsigned)h3<<16);
  o.z = (unsigned)h4 | ((unsigned)h5<<16);
  o.w = (unsigned)h6 | ((unsigned)h7<<16);
  *(uint4*)(LOC + dstE) = o;
  if (lane==0) ewg[(size_t)b*224 + m] = expf(TEMP * ws * inv);
}

struct B2 { bf16x8 x, y; };

// ---------- K6: fused GEMM (MFMA bf16) + top-50 + weighted sum -> atomicAdd bias ----------
// grid (797, 32): x = cn-tile (fast => resident blocks share one LOC slab, TXT L3-resident).
// 256 thr (4 waves). Tile M=224, N=64, K=512 in 16 kc-steps of 32.
// A staged via async global_load_lds (16B) into 2x14336 LDS buffers; no staging VGPRs.
// B loaded straight to registers (struct by value -- no pointer params, no spill).
// Epilogue reuses LDS: 4 phases x 16 cols, S[16][228]+ew = 15.5 KB.
__global__ __launch_bounds__(256,3) void k_main(const u16* __restrict__ TXT, const u16* __restrict__ LOC,
                                                const float* __restrict__ ewg, const float* __restrict__ vbuf,
                                                float* __restrict__ bias){
  __shared__ __align__(16) char smem[28672];
  const int tid = threadIdx.x, lane = tid & 63, wv = tid >> 6;
  const int quad = lane >> 4, l16 = lane & 15;
  const int ms = wv >> 1, ns = wv & 1;
  const int cn0 = blockIdx.x * 64;
  const int b   = blockIdx.y;

  const f32x4 zero = {0.f,0.f,0.f,0.f};
  f32x4 acc[7][2];
  #pragma unroll
  for (int t=0;t<7;++t){ acc[t][0]=zero; acc[t][1]=zero; }

  const u16* Abase = LOC + (size_t)(b*16)*224*32;
  char* Albd0 = smem;
  char* Albd1 = smem + 14336;

  // async stage tile kc (14336 B = 896 x 16B chunks) into dst
  auto stageA = [&](int kc, char* dst){
    const char* src = (const char*)(Abase + (size_t)kc*224*32);
    #pragma unroll
    for (int j=0;j<4;++j){
      int ch0 = j*256 + wv*64;                 // wave-uniform chunk base
      if (ch0 < 896)
        cp16(dst + (size_t)ch0*16, src + (size_t)(ch0 + lane)*16);
    }
  };
  auto loadB = [&](int kc)->B2{
    B2 r;
    size_t e = ((size_t)kc*51008 + (size_t)(cn0 + 32*ns + l16))*32 + quad*8;
    r.x = *(const bf16x8*)(TXT + e);
    r.y = *(const bf16x8*)(TXT + e + 16*32);
    return r;
  };
  auto domfma = [&](const char* Ab, B2 bb){
    #pragma unroll
    for (int t=0;t<7;++t){
      bf16x8 af = *(const bf16x8*)(Ab + (size_t)((112*ms + 16*t + l16)*64 + quad*16));
      acc[t][0] = __builtin_amdgcn_mfma_f32_16x16x32_bf16(af, bb.x, acc[t][0], 0,0,0);
      acc[t][1] = __builtin_amdgcn_mfma_f32_16x16x32_bf16(af, bb.y, acc[t][1], 0,0,0);
    }
  };

  stageA(0, Albd0);
  B2 bcur = loadB(0);
  __syncthreads();                      // drains vmcnt -> buf0 ready

  for (int kc = 0; kc < 16; ++kc){
    char* cur = (kc & 1) ? Albd1 : Albd0;
    char* nxt = (kc & 1) ? Albd0 : Albd1;
    B2 bnext;
    if (kc < 15){
      stageA(kc+1, nxt);                // async into other buffer
      bnext = loadB(kc+1);
    }
    domfma(cur, bcur);
    bcur = bnext;
    __syncthreads();                    // vm drain: nxt filled; lgkm: ds_reads done
  }

  // ---- epilogue: 4 phases x 16 columns; S[16][228] f32 + ew[224] reuse staging LDS ----
  float* S   = (float*)smem;             // 16*228*4 = 14592 B
  float* ewl = (float*)(smem + 14592);   // 224*4 = 896 B
  if (tid < 224) ewl[tid] = ewg[(size_t)b*224 + tid];
  __syncthreads();
  float e0=0.f,e1=0.f,e2=0.f,e3=0.f;
  if (lane < 49){ const float* p = ewl + 4*lane; e0=p[0]; e1=p[1]; e2=p[2]; e3=p[3]; }

  for (int ph=0; ph<4; ++ph){
    if (ns == (ph>>1)){
      int j2 = ph & 1;
      #pragma unroll
      for (int t=0;t<7;++t){
        int m0 = 112*ms + 16*t + quad*4;
        *(f32x4*)(S + (size_t)l16*228 + m0) = (j2 ? acc[t][1] : acc[t][0]);
      }
    }
    __syncthreads();

    #pragma unroll
    for (int i=0;i<4;++i){
      int nl = wv*4 + i;
      int cn = cn0 + ph*16 + nl;
      if (cn < 51000){
        float s0,s1,s2,s3;
        if (lane < 49){
          const float* p = S + (size_t)nl*228 + 4*lane;
          s0=p[0]; s1=p[1]; s2=p[2]; s3=p[3];
        } else { s0=s1=s2=s3=-1e30f; }

        float vmax = wmax(fmaxf(fmaxf(s0,s1),fmaxf(s2,s3)));
        float fmn0 = (lane<49) ? fminf(fminf(s0,s1),fminf(s2,s3)) : 1e30f;
        float vmin = wmin(fmn0);
        float lo = vmin - 1e-6f, hi = vmax + 1e-6f, thr = lo;
        for (int it=0; it<30; ++it){
          float t = 0.5f*(lo+hi);
          unsigned long long b0=__ballot(s0>=t), b1=__ballot(s1>=t), b2=__ballot(s2>=t), b3=__ballot(s3>=t);
          int cnt = __popcll(b0)+__popcll(b1)+__popcll(b2)+__popcll(b3);
          if (cnt==50){ thr=t; break; }
          if (cnt>50) lo=t; else hi=t;
          thr = lo;
        }

        float num=0.f, den=0.f;
        if (s0>=thr){ num += s0*e0; den += e0; }
        if (s1>=thr){ num += s1*e1; den += e1; }
        if (s2>=thr){ num += s2*e2; den += e2; }
        if (s3>=thr){ num += s3*e3; den += e3; }
        num = wsum(num); den = wsum(den);
        if (lane==0){
          int c = cn/51;
          atomicAdd(bias + (size_t)b*1000 + c, vbuf[cn]*(num/den));
        }
      }
    }
    __syncthreads();
  }
}

// ---------- K7: out = fp32( exp(logit_scale) * bias ) ----------
__global__ void k_out(const float* __restrict__ bias, const float* __restrict__ ls, float* __restrict__ out){
  int i = blockIdx.x*256 + threadIdx.x;
  if (i < 32000){
    float sc = expf(ls[0]);
    out[i] = sc * bias[i];
  }
}

// ---------- launch ----------
extern "C" void kernel_launch(void* const* d_in, const int* in_sizes, int n_in,
                              void* d_out, int out_size, void* d_ws, size_t ws_size,
                              hipStream_t stream) {
  const float* img = (const float*)d_in[0];
  const float* loc = (const float*)d_in[1];
  const float* txt = (const float*)d_in[2];
  const float* ls  = (const float*)d_in[3];
  char* ws = (char*)d_ws;
  float* imgn = (float*)(ws + 0);            //  65536
  float* MT   = (float*)(ws + 65536);        //  2048000
  float* invn = (float*)(ws + 2113536);      //  204032
  float* vbuf = (float*)(ws + 2317568);      //  204032
  float* ewg  = (float*)(ws + 2521600);      //  28672
  float* bias = (float*)(ws + 2550272);      //  128000
  u16*   TXT  = (u16*)  (ws + 2678272);      //  52232192
  u16*   LOC  = (u16*)  (ws + 54910464);     //  7340032

  k_img <<<dim3(32),      dim3(64),  0, stream>>>(img, imgn);
  k_txt <<<dim3(51008),   dim3(64),  0, stream>>>(txt, TXT, invn);
  k_mean<<<dim3(1000),    dim3(256), 0, stream>>>(txt, invn, MT);
  k_v   <<<dim3(1000),    dim3(64),  0, stream>>>(TXT, MT, vbuf);
  k_base<<<dim3(1000),    dim3(64),  0, stream>>>(imgn, MT, bias);
  k_loc <<<dim3(224,32),  dim3(64),  0, stream>>>(loc, imgn, LOC, ewg);
  k_main<<<dim3(797,32),  dim3(256), 0, stream>>>(TXT, LOC, ewg, vbuf, bias);
  k_out <<<dim3(125),     dim3(256), 0, stream>>>(bias, ls, (float*)d_out);
}

// Round 5
// 1291.652 us; speedup vs baseline: 4.2163x; 2.7085x over previous
//
#include <hip/hip_runtime.h>
#include <stdint.h>

typedef __bf16  bf16x8 __attribute__((ext_vector_type(8)));
typedef float   f32x4  __attribute__((ext_vector_type(4)));
typedef unsigned short u16;

#define TEMP 5.0f

// ---------- helpers ----------
__device__ inline float wsum(float v){
  #pragma unroll
  for (int off=32; off; off>>=1) v += __shfl_xor(v, off, 64);
  return v;
}
__device__ inline float wmax(float v){
  #pragma unroll
  for (int off=32; off; off>>=1) v = fmaxf(v, __shfl_xor(v, off, 64));
  return v;
}
__device__ inline float wmin(float v){
  #pragma unroll
  for (int off=32; off; off>>=1) v = fminf(v, __shfl_xor(v, off, 64));
  return v;
}
__device__ inline u16 f2bf(float f){               // RNE float->bf16
  unsigned u = __float_as_uint(f);
  u = u + 0x7fffu + ((u>>16)&1u);
  return (u16)(u>>16);
}
__device__ inline float bfl(unsigned u){ return __uint_as_float(u<<16); }
__device__ inline float bfh(unsigned u){ return __uint_as_float(u & 0xffff0000u); }

// async 16B global->LDS: lds dst is WAVE-UNIFORM base, HW adds lane*16
__device__ inline void cp16(void* lds_uniform, const void* g){
  __builtin_amdgcn_global_load_lds(
    (const __attribute__((address_space(1))) unsigned int*)g,
    (__attribute__((address_space(3))) unsigned int*)lds_uniform, 16, 0, 0);
}

// ---------- K0: normalize image features (32x512) ----------
__global__ void k_img(const float* __restrict__ X, float* __restrict__ imgn){
  int b = blockIdx.x, lane = threadIdx.x;
  const float* src = X + (size_t)b*512 + lane*8;
  float4 a = *(const float4*)src;
  float4 c = *(const float4*)(src+4);
  float ss = a.x*a.x+a.y*a.y+a.z*a.z+a.w*a.w + c.x*c.x+c.y*c.y+c.z*c.z+c.w*c.w;
  ss = wsum(ss);
  float inv = 1.0f/sqrtf(ss);
  float* dst = imgn + (size_t)b*512 + lane*8;
  float4 o0 = {a.x*inv,a.y*inv,a.z*inv,a.w*inv};
  float4 o1 = {c.x*inv,c.y*inv,c.z*inv,c.w*inv};
  *(float4*)dst = o0; *(float4*)(dst+4) = o1;
}

// ---------- K1: normalize txt; bf16 K-chunked TXT[kc][cn][32]; invn[n*1000+c] ----------
__global__ void k_txt(const float* __restrict__ X, u16* __restrict__ TXT, float* __restrict__ invn){
  int cn = blockIdx.x, lane = threadIdx.x;
  int kc = lane>>2, kk8 = (lane&3)*8;
  size_t dstE = ((size_t)kc*51008 + cn)*32 + kk8;
  if (cn >= 51000){
    uint4 z = {0,0,0,0};
    *(uint4*)(TXT + dstE) = z;
    return;
  }
  int c = cn/51, n = cn - c*51;
  const float* src = X + ((size_t)n*1000 + c)*512 + lane*8;
  float4 a = *(const float4*)src;
  float4 d = *(const float4*)(src+4);
  float ss = a.x*a.x+a.y*a.y+a.z*a.z+a.w*a.w + d.x*d.x+d.y*d.y+d.z*d.z+d.w*d.w;
  ss = wsum(ss);
  float inv = 1.0f/sqrtf(ss);
  u16 h0=f2bf(a.x*inv),h1=f2bf(a.y*inv),h2=f2bf(a.z*inv),h3=f2bf(a.w*inv);
  u16 h4=f2bf(d.x*inv),h5=f2bf(d.y*inv),h6=f2bf(d.z*inv),h7=f2bf(d.w*inv);
  uint4 o;
  o.x = (unsigned)h0 | ((unsigned)h1<<16);
  o.y = (unsigned)h2 | ((unsigned)h3<<16);
  o.z = (unsigned)h4 | ((unsigned)h5<<16);
  o.w = (unsigned)h6 | ((unsigned)h7<<16);
  *(uint4*)(TXT + dstE) = o;
  if (lane==0) invn[(size_t)n*1000 + c] = inv;
}

// ---------- K2: mean_txt[c] = l2norm( sum_n txt_n[c] ) ----------
__global__ void k_mean(const float* __restrict__ X, const float* __restrict__ invn, float* __restrict__ MT){
  int c = blockIdx.x, tid = threadIdx.x, lane = tid&63, wv = tid>>6;
  __shared__ float sinv[51];
  __shared__ float red[4];
  if (tid < 51) sinv[tid] = invn[(size_t)tid*1000 + c];
  __syncthreads();
  int d0 = tid*2;
  float sx=0.f, sy=0.f;
  for (int n=0;n<51;++n){
    const float2 x = *(const float2*)(X + ((size_t)n*1000 + c)*512 + d0);
    float iv = sinv[n];
    sx += x.x*iv; sy += x.y*iv;
  }
  float ss = sx*sx + sy*sy;
  ss = wsum(ss);
  if (lane==0) red[wv] = ss;
  __syncthreads();
  float tot = red[0]+red[1]+red[2]+red[3];
  float inv = 1.0f/sqrtf(tot);
  float2 o = {sx*inv, sy*inv};
  *(float2*)(MT + (size_t)c*512 + d0) = o;
}

// ---------- K3: v[c,n] = softmax_n( TEMP * mean_txt[c].txt[n,c] ) ----------
__global__ void k_v(const u16* __restrict__ TXT, const float* __restrict__ MT, float* __restrict__ vbuf){
  int c = blockIdx.x, lane = threadIdx.x;
  __shared__ float lg[51];
  const float* mp = MT + (size_t)c*512 + lane*8;
  float4 m0 = *(const float4*)mp;
  float4 m1 = *(const float4*)(mp+4);
  int kc = lane>>2, kk8 = (lane&3)*8;
  for (int n=0;n<51;++n){
    size_t e = ((size_t)kc*51008 + (size_t)(c*51+n))*32 + kk8;
    uint4 q = *(const uint4*)(TXT + e);
    float d = bfl(q.x)*m0.x + bfh(q.x)*m0.y + bfl(q.y)*m0.z + bfh(q.y)*m0.w
            + bfl(q.z)*m1.x + bfh(q.z)*m1.y + bfl(q.w)*m1.z + bfh(q.w)*m1.w;
    d = wsum(d);
    if (lane==0) lg[n] = d;
  }
  __syncthreads();
  float val = (lane<51) ? lg[lane] : -1e30f;
  float mx = wmax(val);
  float e = (lane<51) ? expf(TEMP*(val-mx)) : 0.f;
  float s = wsum(e);
  if (lane<51) vbuf[(size_t)c*51 + lane] = e/s;
}

// ---------- K4: bias[b,c] = base_logits ----------
__global__ void k_base(const float* __restrict__ imgn, const float* __restrict__ MT, float* __restrict__ bias){
  int c = blockIdx.x, lane = threadIdx.x;
  const float* mp = MT + (size_t)c*512 + lane*8;
  float4 m0 = *(const float4*)mp;
  float4 m1 = *(const float4*)(mp+4);
  for (int b=0;b<32;++b){
    const float* ip = imgn + (size_t)b*512 + lane*8;
    float4 i0 = *(const float4*)ip;
    float4 i1 = *(const float4*)(ip+4);
    float d = i0.x*m0.x+i0.y*m0.y+i0.z*m0.z+i0.w*m0.w
            + i1.x*m1.x+i1.y*m1.y+i1.z*m1.z+i1.w*m1.w;
    d = wsum(d);
    if (lane==0) bias[(size_t)b*1000 + c] = d;
  }
}

// ---------- K5: normalize loc; LOC[b][kc][m(224)][32] bf16; ew[b,m] ----------
__global__ void k_loc(const float* __restrict__ L, const float* __restrict__ imgn,
                      u16* __restrict__ LOC, float* __restrict__ ewg){
  int m = blockIdx.x, b = blockIdx.y, lane = threadIdx.x;
  size_t dstE = ((size_t)(b*16 + (lane>>2))*224 + m)*32 + (lane&3)*8;
  if (m >= 196){
    uint4 z = {0,0,0,0};
    *(uint4*)(LOC + dstE) = z;
    if (lane==0) ewg[(size_t)b*224 + m] = 0.f;
    return;
  }
  const float* src = L + ((size_t)b*196 + m)*512 + lane*8;
  float4 a = *(const float4*)src;
  float4 d = *(const float4*)(src+4);
  const float* ip = imgn + (size_t)b*512 + lane*8;
  float4 i0 = *(const float4*)ip;
  float4 i1 = *(const float4*)(ip+4);
  float ss = a.x*a.x+a.y*a.y+a.z*a.z+a.w*a.w + d.x*d.x+d.y*d.y+d.z*d.z+d.w*d.w;
  float ws = a.x*i0.x+a.y*i0.y+a.z*i0.z+a.w*i0.w + d.x*i1.x+d.y*i1.y+d.z*i1.z+d.w*i1.w;
  ss = wsum(ss); ws = wsum(ws);
  float inv = 1.0f/sqrtf(ss);
  u16 h0=f2bf(a.x*inv),h1=f2bf(a.y*inv),h2=f2bf(a.z*inv),h3=f2bf(a.w*inv);
  u16 h4=f2bf(d.x*inv),h5=f2bf(d.y*inv),h6=f2bf(d.z*inv),h7=f2bf(d.w*inv);
  uint4 o;
  o.x = (unsigned)h0 | ((unsigned)h1<<16);
  o.y = (unsigned)h2 | ((unsigned)h3<<16);
  o.z = (unsigned)h4 | ((unsigned)h5<<16);
  o.w = (unsigned)h6 | ((unsigned)h7<<16);
  *(uint4*)(LOC + dstE) = o;
  if (lane==0) ewg[(size_t)b*224 + m] = expf(TEMP * ws * inv);
}

struct B2 { bf16x8 x, y; };

// ---------- K6: fused GEMM (MFMA bf16) + top-50 + weighted sum -> atomicAdd bias ----------
// 1D grid 25504, swizzled into groups of 32 cn-tiles x 32 b (1024 blocks ~= the resident
// set at 4 blocks/CU) so TXT tiles are consumed by all 32 b while L2/L3-hot.
// 256 thr (4 waves). Tile M=224, N=64, K=512 in 16 kc-steps of 32.
// A staged via async global_load_lds (16B) into 2x14336 LDS buffers; no staging VGPRs.
// Epilogue: 4 FULLY-UNROLLED phases (dynamic indexing into acc[] demotes it to scratch
// -> 22 GB of spill traffic; ph must be compile-time!)  S[16][228]+ew = 15.5 KB in LDS.
__global__ __launch_bounds__(256,3) void k_main(const u16* __restrict__ TXT, const u16* __restrict__ LOC,
                                                const float* __restrict__ ewg, const float* __restrict__ vbuf,
                                                float* __restrict__ bias){
  __shared__ __align__(16) char smem[28672];
  const int tid = threadIdx.x, lane = tid & 63, wv = tid >> 6;
  const int quad = lane >> 4, l16 = lane & 15;
  const int ms = wv >> 1, ns = wv & 1;

  // group swizzle: groups of 32 cn-tiles x 32 b; last group 29 x 32
  int id = blockIdx.x, b, cnt_;
  if (id < 24576){
    int g = id >> 10, r = id & 1023;
    b = r >> 5;  cnt_ = (g << 5) + (r & 31);
  } else {
    int r = id - 24576;
    b = r / 29;  cnt_ = 768 + r % 29;
  }
  const int cn0 = cnt_ * 64;

  const f32x4 zero = {0.f,0.f,0.f,0.f};
  f32x4 acc[7][2];
  #pragma unroll
  for (int t=0;t<7;++t){ acc[t][0]=zero; acc[t][1]=zero; }

  const u16* Abase = LOC + (size_t)(b*16)*224*32;
  char* Albd0 = smem;
  char* Albd1 = smem + 14336;

  auto stageA = [&](int kc, char* dst){
    const char* src = (const char*)(Abase + (size_t)kc*224*32);
    #pragma unroll
    for (int j=0;j<4;++j){
      int ch0 = j*256 + wv*64;                 // wave-uniform chunk base
      if (ch0 < 896)
        cp16(dst + (size_t)ch0*16, src + (size_t)(ch0 + lane)*16);
    }
  };
  auto loadB = [&](int kc)->B2{
    B2 r;
    size_t e = ((size_t)kc*51008 + (size_t)(cn0 + 32*ns + l16))*32 + quad*8;
    r.x = *(const bf16x8*)(TXT + e);
    r.y = *(const bf16x8*)(TXT + e + 16*32);
    return r;
  };
  auto domfma = [&](const char* Ab, B2 bb){
    #pragma unroll
    for (int t=0;t<7;++t){
      bf16x8 af = *(const bf16x8*)(Ab + (size_t)((112*ms + 16*t + l16)*64 + quad*16));
      acc[t][0] = __builtin_amdgcn_mfma_f32_16x16x32_bf16(af, bb.x, acc[t][0], 0,0,0);
      acc[t][1] = __builtin_amdgcn_mfma_f32_16x16x32_bf16(af, bb.y, acc[t][1], 0,0,0);
    }
  };

  stageA(0, Albd0);
  B2 bcur = loadB(0);
  __syncthreads();

  for (int kc = 0; kc < 16; ++kc){
    char* cur = (kc & 1) ? Albd1 : Albd0;
    char* nxt = (kc & 1) ? Albd0 : Albd1;
    B2 bnext;
    if (kc < 15){
      stageA(kc+1, nxt);
      bnext = loadB(kc+1);
    }
    domfma(cur, bcur);
    bcur = bnext;
    __syncthreads();
  }

  // ---- epilogue: 4 phases x 16 columns ----
  float* S   = (float*)smem;             // 16*228*4 = 14592 B
  float* ewl = (float*)(smem + 14592);   // 224*4 = 896 B
  if (tid < 224) ewl[tid] = ewg[(size_t)b*224 + tid];
  __syncthreads();
  float e0=0.f,e1=0.f,e2=0.f,e3=0.f;
  if (lane < 49){ const float* p = ewl + 4*lane; e0=p[0]; e1=p[1]; e2=p[2]; e3=p[3]; }

  #pragma unroll
  for (int ph=0; ph<4; ++ph){            // MUST be unrolled: acc index j2 = ph&1
    if (ns == (ph>>1)){
      const int j2 = ph & 1;
      #pragma unroll
      for (int t=0;t<7;++t){
        int m0 = 112*ms + 16*t + quad*4;
        *(f32x4*)(S + (size_t)l16*228 + m0) = acc[t][j2];
      }
    }
    __syncthreads();

    #pragma unroll
    for (int i=0;i<4;++i){
      int nl = wv*4 + i;
      int cn = cn0 + ph*16 + nl;
      if (cn < 51000){
        float s0,s1,s2,s3;
        if (lane < 49){
          const float* p = S + (size_t)nl*228 + 4*lane;
          s0=p[0]; s1=p[1]; s2=p[2]; s3=p[3];
        } else { s0=s1=s2=s3=-1e30f; }

        float vmax = wmax(fmaxf(fmaxf(s0,s1),fmaxf(s2,s3)));
        float fmn0 = (lane<49) ? fminf(fminf(s0,s1),fminf(s2,s3)) : 1e30f;
        float vmin = wmin(fmn0);
        float lo = vmin - 1e-6f, hi = vmax + 1e-6f, thr = lo;
        for (int it=0; it<30; ++it){
          float t = 0.5f*(lo+hi);
          unsigned long long b0=__ballot(s0>=t), b1=__ballot(s1>=t), b2=__ballot(s2>=t), b3=__ballot(s3>=t);
          int cnt = __popcll(b0)+__popcll(b1)+__popcll(b2)+__popcll(b3);
          if (cnt==50){ thr=t; break; }
          if (cnt>50) lo=t; else hi=t;
          thr = lo;
        }

        float num=0.f, den=0.f;
        if (s0>=thr){ num += s0*e0; den += e0; }
        if (s1>=thr){ num += s1*e1; den += e1; }
        if (s2>=thr){ num += s2*e2; den += e2; }
        if (s3>=thr){ num += s3*e3; den += e3; }
        num = wsum(num); den = wsum(den);
        if (lane==0){
          int c = cn/51;
          atomicAdd(bias + (size_t)b*1000 + c, vbuf[cn]*(num/den));
        }
      }
    }
    __syncthreads();
  }
}

// ---------- K7: out = fp32( exp(logit_scale) * bias ) ----------
__global__ void k_out(const float* __restrict__ bias, const float* __restrict__ ls, float* __restrict__ out){
  int i = blockIdx.x*256 + threadIdx.x;
  if (i < 32000){
    float sc = expf(ls[0]);
    out[i] = sc * bias[i];
  }
}

// ---------- launch ----------
extern "C" void kernel_launch(void* const* d_in, const int* in_sizes, int n_in,
                              void* d_out, int out_size, void* d_ws, size_t ws_size,
                              hipStream_t stream) {
  const float* img = (const float*)d_in[0];
  const float* loc = (const float*)d_in[1];
  const float* txt = (const float*)d_in[2];
  const float* ls  = (const float*)d_in[3];
  char* ws = (char*)d_ws;
  float* imgn = (float*)(ws + 0);            //  65536
  float* MT   = (float*)(ws + 65536);        //  2048000
  float* invn = (float*)(ws + 2113536);      //  204032
  float* vbuf = (float*)(ws + 2317568);      //  204032
  float* ewg  = (float*)(ws + 2521600);      //  28672
  float* bias = (float*)(ws + 2550272);      //  128000
  u16*   TXT  = (u16*)  (ws + 2678272);      //  52232192
  u16*   LOC  = (u16*)  (ws + 54910464);     //  7340032

  k_img <<<dim3(32),      dim3(64),  0, stream>>>(img, imgn);
  k_txt <<<dim3(51008),   dim3(64),  0, stream>>>(txt, TXT, invn);
  k_mean<<<dim3(1000),    dim3(256), 0, stream>>>(txt, invn, MT);
  k_v   <<<dim3(1000),    dim3(64),  0, stream>>>(TXT, MT, vbuf);
  k_base<<<dim3(1000),    dim3(64),  0, stream>>>(imgn, MT, bias);
  k_loc <<<dim3(224,32),  dim3(64),  0, stream>>>(loc, imgn, LOC, ewg);
  k_main<<<dim3(25504),   dim3(256), 0, stream>>>(TXT, LOC, ewg, vbuf, bias);
  k_out <<<dim3(125),     dim3(256), 0, stream>>>(bias, ls, (float*)d_out);
}